// Round 8
// baseline (1296.502 us; speedup 1.0000x reference)
//
#include <hip/hip_runtime.h>
#include <stdint.h>
#include <math.h>

// Bit-exact canonical-f32 sparse fold (validated rounds 4-7, absmax 0.0):
// y[r][j] = ascending-k f32 FMA fold over nonzero masked weights, + bias,
// * boost, exact radix top-k on f32 t-bits, keep ties (>=).
//
// Round 8 (R6 base, R7 reverted):
//  - fold: branch-free 2-stage pipeline. pairT rows < MAXE are zero-filled, so
//    rows e+1/e+2 prefetch unconditionally (fmaf(0) no-op). No exec-mask churn,
//    no register copies. __launch_bounds__(256,4) = 128-VGPR cap.
//  - select: keep sorted order through selection (permutation-invariant);
//    bias/boost via orig-indexed L1 loads; ONE histogram pass per round for
//    all 4 rows (hist[4][256], wave w scans row w); LDS scatter only at the
//    final store. Barriers ~56 -> ~12 per block.

#define BATCH 16384
#define K_DIM 512
#define N_DIM 4096
#define RPB 4
#define MAXE 64

typedef float f32x4 __attribute__((ext_vector_type(4)));
typedef unsigned int u32;

// ---------- boost table ----------
__global__ void boost_kernel(const float* __restrict__ duty,
                             const int* __restrict__ kptr,
                             float* __restrict__ boost) {
  const int j = blockIdx.x * blockDim.x + threadIdx.x;
  if (j < N_DIM) {
    const float td = (float)((double)kptr[0] / (double)N_DIM);
    const float arg = 0.5f * (td - duty[j]);      // f32 ops, as reference
    boost[j] = (float)exp((double)arg);           // correctly-rounded f32 exp
  }
}

// ---------- compress: per-column nonzeros, ascending k ----------
__global__ __launch_bounds__(256) void compress_kernel(
    const float* __restrict__ W, const float* __restrict__ mask,
    unsigned short* __restrict__ cIdx, float* __restrict__ cVal,
    int* __restrict__ cnt) {
  const int j = blockIdx.x * 4 + (threadIdx.x >> 6);  // one wave per column
  const int lane = threadIdx.x & 63;
  if (j >= N_DIM) return;
  const float* mr = mask + (size_t)j * K_DIM;
  const float* wr = W + (size_t)j * K_DIM;
  int base = 0;
#pragma unroll
  for (int c = 0; c < K_DIM / 64; ++c) {
    const int k = c * 64 + lane;
    const bool act = (mr[k] != 0.0f);
    const unsigned long long bal = __ballot(act);
    const int pos = __popcll(bal & ((1ull << lane) - 1ull));
    if (act && base + pos < MAXE) {
      cIdx[(size_t)j * MAXE + base + pos] = (unsigned short)k;
      cVal[(size_t)j * MAXE + base + pos] = wr[k];   // mask==1 -> exact
    }
    base += (int)__popcll(bal);
  }
  if (lane == 0) cnt[j] = base < MAXE ? base : MAXE;
}

// ---------- counting sort of columns by nnz; per-thread loop bounds ----------
__global__ __launch_bounds__(256) void sort_kernel(
    const int* __restrict__ cnt, int* __restrict__ perm, int* __restrict__ tE) {
  __shared__ int hist[MAXE + 1];
  __shared__ int off[MAXE + 1];
  const int tid = threadIdx.x;
  if (tid <= MAXE) hist[tid] = 0;
  __syncthreads();
  for (int j = tid; j < N_DIM; j += 256) atomicAdd(&hist[cnt[j]], 1);
  __syncthreads();
  if (tid == 0) {
    int s = 0;
    for (int c = 0; c <= MAXE; ++c) { off[c] = s; s += hist[c]; }
  }
  __syncthreads();
  for (int j = tid; j < N_DIM; j += 256) {
    const int p = atomicAdd(&off[cnt[j]], 1);
    perm[p] = j;                                   // ascending count
  }
  __syncthreads();
  // thread t owns sorted ranks [t*16, t*16+16); max count = last rank's count
  tE[tid] = cnt[perm[tid * 16 + 15]];
}

// ---------- fill transposed padded pair array in slot order ----------
__global__ __launch_bounds__(256) void fill_kernel(
    const unsigned short* __restrict__ cIdx, const float* __restrict__ cVal,
    const int* __restrict__ cnt, const int* __restrict__ perm,
    uint2* __restrict__ pairT, int* __restrict__ orig) {
  const int s = blockIdx.x * 256 + threadIdx.x;    // sorted rank 0..4095
  const int j = perm[s];
  const int c = cnt[j];
  const int slot = (s & 15) * 256 + (s >> 4);      // u*256 + tid
  orig[slot] = j;
#pragma unroll 4
  for (int e = 0; e < MAXE; ++e) {
    uint2 pr;
    if (e < c) {
      pr.x = (u32)cIdx[(size_t)j * MAXE + e] * 16u; // LDS byte offset (k*16)
      pr.y = __float_as_uint(cVal[(size_t)j * MAXE + e]);
    } else {
      pr.x = 0u; pr.y = 0u;                         // fmaf(0,..) no-op
    }
    pairT[(size_t)e * N_DIM + slot] = pr;
  }
}

// ---------- fused gather-GEMM + exact top-k select ----------
__global__ __launch_bounds__(256, 4) void fused_kernel(
    const float* __restrict__ x, const float* __restrict__ bvec,
    const uint2* __restrict__ pairT, const float* __restrict__ boost,
    const int* __restrict__ orig, const int* __restrict__ tE,
    const int* __restrict__ kptr, float* __restrict__ out) {
  // smem: x tile [512][4] (8 KB) during fold; one y row [4096] at store time
  __shared__ __align__(16) float smem[N_DIM];
  __shared__ u32 hist[4 * 256];
  __shared__ u32 s_prefix[4], s_kk[4];

  const int tid = threadIdx.x;
  const int row0 = blockIdx.x * RPB;

  // stage RPB rows of x: smem[k*4 + r]
  for (int i = tid; i < K_DIM; i += 256)
#pragma unroll
    for (int r = 0; r < RPB; ++r)
      smem[i * 4 + r] = x[(size_t)(row0 + r) * K_DIM + i];

  const int myE = tE[tid];
  const int kk0 = kptr[0];
  float a[RPB][16];
#pragma unroll
  for (int r = 0; r < RPB; ++r)
#pragma unroll
    for (int u = 0; u < 16; ++u) a[r][u] = 0.0f;
  __syncthreads();

  // branch-free pipelined gather fold (rows <= MAXE-1 all valid, zero-padded)
  uint2 prA[16], prB[16];
  {
    const uint2* p0 = pairT + tid;
#pragma unroll
    for (int u = 0; u < 16; ++u) prA[u] = p0[u * 256];
  }
  int e = 0;
  for (; e + 2 <= myE; e += 2) {
    const uint2* p1 = pairT + (size_t)(e + 1) * N_DIM + tid;
#pragma unroll
    for (int u = 0; u < 16; ++u) prB[u] = p1[u * 256];
#pragma unroll
    for (int u = 0; u < 16; ++u) {                  // row e
      const f32x4 xs = *(const f32x4*)((const char*)smem + prA[u].x);
      const float w = __uint_as_float(prA[u].y);
      a[0][u] = fmaf(w, xs[0], a[0][u]);
      a[1][u] = fmaf(w, xs[1], a[1][u]);
      a[2][u] = fmaf(w, xs[2], a[2][u]);
      a[3][u] = fmaf(w, xs[3], a[3][u]);
    }
    const uint2* p2 = pairT + (size_t)(e + 2) * N_DIM + tid;
#pragma unroll
    for (int u = 0; u < 16; ++u) prA[u] = p2[u * 256];
#pragma unroll
    for (int u = 0; u < 16; ++u) {                  // row e+1
      const f32x4 xs = *(const f32x4*)((const char*)smem + prB[u].x);
      const float w = __uint_as_float(prB[u].y);
      a[0][u] = fmaf(w, xs[0], a[0][u]);
      a[1][u] = fmaf(w, xs[1], a[1][u]);
      a[2][u] = fmaf(w, xs[2], a[2][u]);
      a[3][u] = fmaf(w, xs[3], a[3][u]);
    }
  }
  if (e < myE) {                                    // odd remainder
#pragma unroll
    for (int u = 0; u < 16; ++u) {
      const f32x4 xs = *(const f32x4*)((const char*)smem + prA[u].x);
      const float w = __uint_as_float(prA[u].y);
      a[0][u] = fmaf(w, xs[0], a[0][u]);
      a[1][u] = fmaf(w, xs[1], a[1][u]);
      a[2][u] = fmaf(w, xs[2], a[2][u]);
      a[3][u] = fmaf(w, xs[3], a[3][u]);
    }
  }

  // bias + boost in SORTED order (selection is permutation-invariant)
  int origId[16];
  float bl[16];
#pragma unroll
  for (int u = 0; u < 16; ++u) origId[u] = orig[u * 256 + tid];
#pragma unroll
  for (int u = 0; u < 16; ++u) {
    const float bj = bvec[origId[u]];
    bl[u] = boost[origId[u]];
#pragma unroll
    for (int r = 0; r < RPB; ++r) a[r][u] += bj;    // y, single f32 add
  }

  if (tid < 4) { s_prefix[tid] = 0u; s_kk[tid] = (u32)kk0; }

  // 4 radix rounds, all RPB rows per pass; wave w scans row w
#pragma unroll 1
  for (int round = 0; round < 4; ++round) {
    const int shift = 24 - 8 * round;
    const u32 himask = round ? (0xFFFFFFFFu << (32 - 8 * round)) : 0u;
#pragma unroll
    for (int q = 0; q < 4; ++q) hist[q * 256 + tid] = 0u;
    __syncthreads();
#pragma unroll
    for (int r = 0; r < RPB; ++r) {
      const u32 prefix = s_prefix[r];
#pragma unroll
      for (int u = 0; u < 16; ++u) {
        const float t = a[r][u] * bl[u];            // single f32 mult
        const u32 v = __float_as_uint(t);
        const u32 key = (v & 0x80000000u) ? ~v : (v | 0x80000000u);
        if ((key & himask) == prefix)
          atomicAdd(&hist[r * 256 + ((key >> shift) & 255u)], 1u);
      }
    }
    __syncthreads();
    {
      const int w = tid >> 6;                       // wave w handles row w
      const int l = tid & 63;
      const u32 kk = s_kk[w];
      const u32 prefix = s_prefix[w];
      const u32 h0 = hist[w * 256 + l * 4],     h1 = hist[w * 256 + l * 4 + 1];
      const u32 h2 = hist[w * 256 + l * 4 + 2], h3 = hist[w * 256 + l * 4 + 3];
      const u32 s3 = h3, s2 = h2 + s3, s1 = h1 + s2, s0 = h0 + s1;
      u32 t = s0;
#pragma unroll
      for (int off = 1; off < 64; off <<= 1) {
        const u32 v = __shfl_down(t, off, 64);
        if (l + off < 64) t += v;
      }
      const u32 Eab = t - s0;                       // lanes strictly above
      const u32 S[5] = {Eab + s0, Eab + s1, Eab + s2, Eab + s3, Eab};
#pragma unroll
      for (int i = 0; i < 4; ++i)
        if (S[i] >= kk && S[i + 1] < kk) {          // unique winner lane
          s_prefix[w] = prefix | ((u32)(l * 4 + i) << shift);
          s_kk[w] = kk - S[i + 1];
        }
    }
    __syncthreads();
  }

  // store: mask, scatter to original order via LDS, coalesced global write
#pragma unroll 1
  for (int r = 0; r < RPB; ++r) {
    const u32 tkey = s_prefix[r];
    __syncthreads();                                // smem free
#pragma unroll
    for (int u = 0; u < 16; ++u) {
      const float t = a[r][u] * bl[u];
      const u32 v = __float_as_uint(t);
      const u32 key = (v & 0x80000000u) ? ~v : (v | 0x80000000u);
      smem[origId[u]] = (key >= tkey) ? a[r][u] : 0.0f;
    }
    __syncthreads();
    float* orow = out + (size_t)(row0 + r) * N_DIM;
#pragma unroll
    for (int u = 0; u < 16; ++u)
      orow[u * 256 + tid] = smem[u * 256 + tid];
  }
}

extern "C" void kernel_launch(void* const* d_in, const int* in_sizes, int n_in,
                              void* d_out, int out_size, void* d_ws, size_t ws_size,
                              hipStream_t stream) {
  const float* x     = (const float*)d_in[0];
  const float* W     = (const float*)d_in[1];
  const float* bvec  = (const float*)d_in[2];
  const float* wmask = (const float*)d_in[3];
  const float* duty  = (const float*)d_in[4];
  const int* kptr    = (const int*)d_in[5];
  float* out = (float*)d_out;

  uint8_t* ws = (uint8_t*)d_ws;
  unsigned short* cIdx = (unsigned short*)(ws);                 // 512 KiB
  float* cVal          = (float*)(ws + (1u << 20));             // 1 MiB
  int* cnt             = (int*)(ws + (2u << 20));               // 16 KiB
  float* boost         = (float*)(ws + (2u << 20) + (64u << 10));
  int* perm            = (int*)(ws + (2u << 20) + (128u << 10)); // 16 KiB
  int* tE              = (int*)(ws + (2u << 20) + (192u << 10)); // 1 KiB
  int* orig            = (int*)(ws + (2u << 20) + (256u << 10)); // 16 KiB
  uint2* pairT         = (uint2*)(ws + (4u << 20));             // 2 MiB

  boost_kernel<<<16, 256, 0, stream>>>(duty, kptr, boost);
  compress_kernel<<<N_DIM / 4, 256, 0, stream>>>(W, wmask, cIdx, cVal, cnt);
  sort_kernel<<<1, 256, 0, stream>>>(cnt, perm, tE);
  fill_kernel<<<N_DIM / 256, 256, 0, stream>>>(cIdx, cVal, cnt, perm, pairT, orig);
  fused_kernel<<<BATCH / RPB, 256, 0, stream>>>(x, bvec, pairT, boost, orig, tE,
                                                kptr, out);
}

// Round 9
// 1159.204 us; speedup vs baseline: 1.1184x; 1.1184x over previous
//
#include <hip/hip_runtime.h>
#include <stdint.h>
#include <math.h>

// Bit-exact canonical-f32 sparse fold (validated rounds 4-8, absmax 0.0):
// y[r][j] = ascending-k f32 FMA fold over nonzero masked weights, + bias,
// * boost, exact top-k on f32 t values, keep ties (>=).
//
// Round 9 (R6 base; fold untouched): select overhaul.
//  - radix select on fixed-point key U = int(t*2^28) (sign-flipped): monotone,
//    spreads round-0 digits over ~80 bins (f32-bit keys clustered ~6 bins ->
//    11-way LDS same-address atomic serialization, ~120us of LDS pipe).
//  - exactness: tie class {U==Uk} re-ranked by exact f32 key, keep s_kk
//    largest with >= duplicate semantics -> selection still bit-exact.
//  - keys recomputed per use (not stored); select in sorted order, scatter to
//    original order only at store -> lower live state, less scratch spill.

#define BATCH 16384
#define K_DIM 512
#define N_DIM 4096
#define RPB 4
#define MAXE 64
#define TCAP 16

typedef float f32x4 __attribute__((ext_vector_type(4)));
typedef unsigned int u32;

// ---------- boost table ----------
__global__ void boost_kernel(const float* __restrict__ duty,
                             const int* __restrict__ kptr,
                             float* __restrict__ boost) {
  const int j = blockIdx.x * blockDim.x + threadIdx.x;
  if (j < N_DIM) {
    const float td = (float)((double)kptr[0] / (double)N_DIM);
    const float arg = 0.5f * (td - duty[j]);      // f32 ops, as reference
    boost[j] = (float)exp((double)arg);           // correctly-rounded f32 exp
  }
}

// ---------- compress: per-column nonzeros, ascending k ----------
__global__ __launch_bounds__(256) void compress_kernel(
    const float* __restrict__ W, const float* __restrict__ mask,
    unsigned short* __restrict__ cIdx, float* __restrict__ cVal,
    int* __restrict__ cnt) {
  const int j = blockIdx.x * 4 + (threadIdx.x >> 6);  // one wave per column
  const int lane = threadIdx.x & 63;
  if (j >= N_DIM) return;
  const float* mr = mask + (size_t)j * K_DIM;
  const float* wr = W + (size_t)j * K_DIM;
  int base = 0;
#pragma unroll
  for (int c = 0; c < K_DIM / 64; ++c) {
    const int k = c * 64 + lane;
    const bool act = (mr[k] != 0.0f);
    const unsigned long long bal = __ballot(act);
    const int pos = __popcll(bal & ((1ull << lane) - 1ull));
    if (act && base + pos < MAXE) {
      cIdx[(size_t)j * MAXE + base + pos] = (unsigned short)k;
      cVal[(size_t)j * MAXE + base + pos] = wr[k];   // mask==1 -> exact
    }
    base += (int)__popcll(bal);
  }
  if (lane == 0) cnt[j] = base < MAXE ? base : MAXE;
}

// ---------- counting sort of columns by nnz; per-thread loop bounds ----------
__global__ __launch_bounds__(256) void sort_kernel(
    const int* __restrict__ cnt, int* __restrict__ perm, int* __restrict__ tE) {
  __shared__ int hist[MAXE + 1];
  __shared__ int off[MAXE + 1];
  const int tid = threadIdx.x;
  if (tid <= MAXE) hist[tid] = 0;
  __syncthreads();
  for (int j = tid; j < N_DIM; j += 256) atomicAdd(&hist[cnt[j]], 1);
  __syncthreads();
  if (tid == 0) {
    int s = 0;
    for (int c = 0; c <= MAXE; ++c) { off[c] = s; s += hist[c]; }
  }
  __syncthreads();
  for (int j = tid; j < N_DIM; j += 256) {
    const int p = atomicAdd(&off[cnt[j]], 1);
    perm[p] = j;                                   // ascending count
  }
  __syncthreads();
  // thread t owns sorted ranks [t*16, t*16+16); max count = last rank's count
  tE[tid] = cnt[perm[tid * 16 + 15]];
}

// ---------- fill transposed padded pair array in slot order ----------
__global__ __launch_bounds__(256) void fill_kernel(
    const unsigned short* __restrict__ cIdx, const float* __restrict__ cVal,
    const int* __restrict__ cnt, const int* __restrict__ perm,
    uint2* __restrict__ pairT, int* __restrict__ orig) {
  const int s = blockIdx.x * 256 + threadIdx.x;    // sorted rank 0..4095
  const int j = perm[s];
  const int c = cnt[j];
  const int slot = (s & 15) * 256 + (s >> 4);      // u*256 + tid
  orig[slot] = j;
#pragma unroll 4
  for (int e = 0; e < MAXE; ++e) {
    uint2 pr;
    if (e < c) {
      pr.x = (u32)cIdx[(size_t)j * MAXE + e] * 16u; // LDS byte offset (k*16)
      pr.y = __float_as_uint(cVal[(size_t)j * MAXE + e]);
    } else {
      pr.x = 0u; pr.y = 0u;                         // fmaf(0,..) no-op
    }
    pairT[(size_t)e * N_DIM + slot] = pr;
  }
}

static __device__ __forceinline__ u32 ikey(float t) {
  float s = t * 268435456.0f;                       // 2^28
  s = fminf(fmaxf(s, -2.1e9f), 2.1e9f);             // monotone clamp
  return ((u32)(int)s) ^ 0x80000000u;               // signed -> unsigned order
}
static __device__ __forceinline__ u32 fkey(float t) {
  const u32 v = __float_as_uint(t);
  return (v & 0x80000000u) ? ~v : (v | 0x80000000u);
}

// ---------- fused gather-GEMM + exact top-k select ----------
__global__ void fused_kernel(
    const float* __restrict__ x, const float* __restrict__ bvec,
    const uint2* __restrict__ pairT, const float* __restrict__ boost,
    const int* __restrict__ orig, const int* __restrict__ tE,
    const int* __restrict__ kptr, float* __restrict__ out) {
  // smem: x tile [512][4] (8 KB) during fold; scatter row [4096] at store
  __shared__ __align__(16) float smem[N_DIM];
  __shared__ u32 hist[256];
  __shared__ u32 s_prefix, s_kk, s_cut;
  __shared__ int s_tc;
  __shared__ u32 s_tie[TCAP];

  const int tid = threadIdx.x;
  const int row0 = blockIdx.x * RPB;

  // stage RPB rows of x: smem[k*4 + r]
  for (int i = tid; i < K_DIM; i += 256)
#pragma unroll
    for (int r = 0; r < RPB; ++r)
      smem[i * 4 + r] = x[(size_t)(row0 + r) * K_DIM + i];

  const int myE = tE[tid];
  const int kk0 = kptr[0];
  float a[RPB][16];
#pragma unroll
  for (int r = 0; r < RPB; ++r)
#pragma unroll
    for (int u = 0; u < 16; ++u) a[r][u] = 0.0f;
  __syncthreads();

  // gather fold (R6 verbatim): per-lane bound myE, zero-pad no-ops
  for (int e = 0; e < myE; ++e) {
    const uint2* pe = pairT + (size_t)e * N_DIM + tid;
#pragma unroll
    for (int u = 0; u < 16; ++u) {
      const uint2 pr = pe[u * 256];                 // coalesced dwordx2
      const f32x4 xs = *(const f32x4*)((const char*)smem + pr.x);
      const float w = __uint_as_float(pr.y);
      a[0][u] = fmaf(w, xs[0], a[0][u]);
      a[1][u] = fmaf(w, xs[1], a[1][u]);
      a[2][u] = fmaf(w, xs[2], a[2][u]);
      a[3][u] = fmaf(w, xs[3], a[3][u]);
    }
  }

  // bias + boost in SORTED order (selection is permutation-invariant)
  float bl[16];
#pragma unroll
  for (int u = 0; u < 16; ++u) {
    const int j = orig[u * 256 + tid];
    const float bj = bvec[j];
    bl[u] = boost[j];
#pragma unroll
    for (int r = 0; r < RPB; ++r) a[r][u] += bj;    // y, single f32 add
  }

  // per-row select on int keys + exact f32 tie resolution
#pragma unroll 1
  for (int r = 0; r < RPB; ++r) {
    __syncthreads();                                // hist/s_/smem free
    if (tid == 0) { s_prefix = 0u; s_kk = (u32)kk0; s_tc = 0; s_cut = 0u; }

#pragma unroll 1
    for (int round = 0; round < 4; ++round) {
      const int shift = 24 - 8 * round;
      const u32 himask = round ? (0xFFFFFFFFu << (32 - 8 * round)) : 0u;
      hist[tid] = 0u;
      __syncthreads();
      const u32 prefix = s_prefix;
      const u32 kk = s_kk;
#pragma unroll
      for (int u = 0; u < 16; ++u) {
        const u32 U = ikey(a[r][u] * bl[u]);        // recomputed, not stored
        if ((U & himask) == prefix)
          atomicAdd(&hist[(U >> shift) & 255u], 1u);
      }
      __syncthreads();
      if (tid < 64) {                               // wave 0: suffix scan
        const int l = tid;
        const u32 h0 = hist[l * 4],     h1 = hist[l * 4 + 1];
        const u32 h2 = hist[l * 4 + 2], h3 = hist[l * 4 + 3];
        const u32 s3 = h3, s2 = h2 + s3, s1 = h1 + s2, s0 = h0 + s1;
        u32 t = s0;
#pragma unroll
        for (int off = 1; off < 64; off <<= 1) {
          const u32 v = __shfl_down(t, off, 64);
          if (l + off < 64) t += v;
        }
        const u32 Eab = t - s0;                     // lanes strictly above
        const u32 S[5] = {Eab + s0, Eab + s1, Eab + s2, Eab + s3, Eab};
#pragma unroll
        for (int i = 0; i < 4; ++i)
          if (S[i] >= kk && S[i + 1] < kk) {        // unique winner lane
            s_prefix = prefix | ((u32)(l * 4 + i) << shift);
            s_kk = kk - S[i + 1];
          }
      }
      __syncthreads();
    }
    const u32 Uk = s_prefix;                        // k-th largest int key
    // tie pass: collect exact f32 keys of the U==Uk class
#pragma unroll
    for (int u = 0; u < 16; ++u) {
      const float t = a[r][u] * bl[u];
      if (ikey(t) == Uk) {
        const int idx = atomicAdd(&s_tc, 1);
        if (idx < TCAP) s_tie[idx] = fkey(t);
      }
    }
    __syncthreads();
    if (tid == 0) {
      const int C = s_tc < TCAP ? s_tc : TCAP;
      const int m = (int)s_kk;                      // # of ties to keep
      u32 cut = 0u;                                 // keep all ties if m >= C
      if (m < C) {
        // cut = m-th largest tie key (m >= 1)
        u32 vals[TCAP];
        for (int i = 0; i < C; ++i) vals[i] = s_tie[i];
        for (int t2 = 0; t2 < m; ++t2) {
          int best = 0; u32 bv = 0u;
          for (int i = 0; i < C; ++i)
            if (vals[i] >= bv) { bv = vals[i]; best = i; }
          cut = bv; vals[best] = 0u;
        }
      }
      s_cut = cut;
    }
    __syncthreads();
    const u32 cut = s_cut;

    // mask + scatter to original order + coalesced store
#pragma unroll
    for (int u = 0; u < 16; ++u) {
      const float t = a[r][u] * bl[u];
      const u32 U = ikey(t);
      const bool win = (U > Uk) || (U == Uk && fkey(t) >= cut);
      smem[orig[u * 256 + tid]] = win ? a[r][u] : 0.0f;
    }
    __syncthreads();
    float* orow = out + (size_t)(row0 + r) * N_DIM;
#pragma unroll
    for (int u = 0; u < 16; ++u)
      orow[u * 256 + tid] = smem[u * 256 + tid];
  }
}

extern "C" void kernel_launch(void* const* d_in, const int* in_sizes, int n_in,
                              void* d_out, int out_size, void* d_ws, size_t ws_size,
                              hipStream_t stream) {
  const float* x     = (const float*)d_in[0];
  const float* W     = (const float*)d_in[1];
  const float* bvec  = (const float*)d_in[2];
  const float* wmask = (const float*)d_in[3];
  const float* duty  = (const float*)d_in[4];
  const int* kptr    = (const int*)d_in[5];
  float* out = (float*)d_out;

  uint8_t* ws = (uint8_t*)d_ws;
  unsigned short* cIdx = (unsigned short*)(ws);                 // 512 KiB
  float* cVal          = (float*)(ws + (1u << 20));             // 1 MiB
  int* cnt             = (int*)(ws + (2u << 20));               // 16 KiB
  float* boost         = (float*)(ws + (2u << 20) + (64u << 10));
  int* perm            = (int*)(ws + (2u << 20) + (128u << 10)); // 16 KiB
  int* tE              = (int*)(ws + (2u << 20) + (192u << 10)); // 1 KiB
  int* orig            = (int*)(ws + (2u << 20) + (256u << 10)); // 16 KiB
  uint2* pairT         = (uint2*)(ws + (4u << 20));             // 2 MiB

  boost_kernel<<<16, 256, 0, stream>>>(duty, kptr, boost);
  compress_kernel<<<N_DIM / 4, 256, 0, stream>>>(W, wmask, cIdx, cVal, cnt);
  sort_kernel<<<1, 256, 0, stream>>>(cnt, perm, tE);
  fill_kernel<<<N_DIM / 256, 256, 0, stream>>>(cIdx, cVal, cnt, perm, pairT, orig);
  fused_kernel<<<BATCH / RPB, 256, 0, stream>>>(x, bvec, pairT, boost, orig, tE,
                                                kptr, out);
}